// Round 15
// baseline (4387.328 us; speedup 1.0000x reference)
//
#include <hip/hip_runtime.h>

constexpr int TIN = 50;
constexpr int BLK = 256;
constexpr float NEG_LOG2E = -1.44269504088896341f;

typedef float floatx4 __attribute__((ext_vector_type(4)));

// ws float layout (16B-aligned). Gate-PAIR packed, zero padding.
// Pair A = (i, g): 20 floats = [i0..i9, g0..g9]; i scaled by -log2e, g raw.
// Pair B = (f, o): 20 floats = [f0..f9, o0..o9]; both scaled by -log2e.
// sigmoid(z) = rcp(1 + exp2(z')) on prescaled z'.
//   0    R1A[10][20]   200
//   200  R1B[10][20]   200
//   400  W1A[20]
//   420  W1B[20]
//   440  b1A[20]
//   460  b1B[20]
//   480  W2A[10][20]   200
//   680  W2B[10][20]   200
//   880  b2A[20]
//   900  b2B[20]
//   920  R2A[10][20]   200
//   1120 R2B[10][20]   200
//   1320 Wd[10] + pad
constexpr int WS_FLOATS = 1332;

__global__ void prep_weights(const float* __restrict__ W1, const float* __restrict__ R1,
                             const float* __restrict__ b1, const float* __restrict__ W2,
                             const float* __restrict__ R2, const float* __restrict__ b2,
                             const float* __restrict__ Wd, float* __restrict__ ws)
{
    const int tid = threadIdx.x;
    for (int i = tid; i < 200; i += BLK) {
        const int u = i / 20, k = i % 20;
        const int colA = (k < 10) ? k : 20 + (k - 10);          // i | g
        const float sA  = (k < 10) ? NEG_LOG2E : 1.0f;
        const int colB = (k < 10) ? 10 + k : 30 + (k - 10);     // f | o
        ws[i]          = R1[u * 40 + colA] * sA;
        ws[200 + i]    = R1[u * 40 + colB] * NEG_LOG2E;
        ws[480 + i]    = W2[u * 40 + colA] * sA;
        ws[680 + i]    = W2[u * 40 + colB] * NEG_LOG2E;
        ws[920 + i]    = R2[u * 40 + colA] * sA;
        ws[1120 + i]   = R2[u * 40 + colB] * NEG_LOG2E;
    }
    for (int k = tid; k < 20; k += BLK) {
        const int colA = (k < 10) ? k : 20 + (k - 10);
        const float sA  = (k < 10) ? NEG_LOG2E : 1.0f;
        const int colB = (k < 10) ? 10 + k : 30 + (k - 10);
        ws[400 + k] = W1[colA] * sA;
        ws[420 + k] = W1[colB] * NEG_LOG2E;
        ws[440 + k] = b1[colA] * sA;
        ws[460 + k] = b1[colB] * NEG_LOG2E;
        ws[880 + k] = b2[colA] * sA;
        ws[900 + k] = b2[colB] * NEG_LOG2E;
    }
    if (tid < 12) ws[1320 + tid] = (tid < 10) ? Wd[tid] : 0.0f;
}

#define EFMA __builtin_elementwise_fma
#define SB   __builtin_amdgcn_sched_barrier(0);
#define SIGS(x) __builtin_amdgcn_rcpf(1.0f + __builtin_amdgcn_exp2f(x))

// element k (0..19) of a 5-quad group, k literal -> compile-time register pick
#define EL5(q0,q1,q2,q3,q4,k)                                                 \
    ((k)<4?(q0)[(k)]:(k)<8?(q1)[(k)-4]:(k)<12?(q2)[(k)-8]:                    \
     (k)<16?(q3)[(k)-12]:(q4)[(k)-16])

#define ELA(k) EL5(tA0,tA1,tA2,tA3,tA4,(k))
#define ELB(k) EL5(tB0,tB1,tB2,tB3,tB4,(k))

// ---------------- M=2 main-loop blocks -------------------------------------
// t init: t = x*W + b (pair chunk, 5 quads, both elements; 10 shared loads)
#define INIT2(WQ, BQ)                                                         \
  { const floatx4 w0_=(WQ)[0], w1_=(WQ)[1], w2_=(WQ)[2], w3_=(WQ)[3],         \
                  w4_=(WQ)[4];                                                \
    const floatx4 c0_=(BQ)[0], c1_=(BQ)[1], c2_=(BQ)[2], c3_=(BQ)[3],         \
                  c4_=(BQ)[4];                                                \
    tA0=EFMA(xsA_,w0_,c0_); tB0=EFMA(xsB_,w0_,c0_);                           \
    tA1=EFMA(xsA_,w1_,c1_); tB1=EFMA(xsB_,w1_,c1_);                           \
    tA2=EFMA(xsA_,w2_,c2_); tB2=EFMA(xsB_,w2_,c2_);                           \
    tA3=EFMA(xsA_,w3_,c3_); tB3=EFMA(xsB_,w3_,c3_);                           \
    tA4=EFMA(xsA_,w4_,c4_); tB4=EFMA(xsB_,w4_,c4_); }

// one source unit: 5 shared quad loads, 10 quad-FMAs; SB at consumption edge
#define RECU2(RQ, u, HA, HB)                                                  \
  { const floatx4 r0_=(RQ)[(u)*5+0], r1_=(RQ)[(u)*5+1], r2_=(RQ)[(u)*5+2],    \
                  r3_=(RQ)[(u)*5+3], r4_=(RQ)[(u)*5+4];                       \
    const float ha_=(HA), hb_=(HB);                                           \
    const floatx4 hav_={ha_,ha_,ha_,ha_}, hbv_={hb_,hb_,hb_,hb_};             \
    tA0=EFMA(hav_,r0_,tA0); tB0=EFMA(hbv_,r0_,tB0);                           \
    tA1=EFMA(hav_,r1_,tA1); tB1=EFMA(hbv_,r1_,tB1);                           \
    tA2=EFMA(hav_,r2_,tA2); tB2=EFMA(hbv_,r2_,tB2);                           \
    tA3=EFMA(hav_,r3_,tA3); tB3=EFMA(hbv_,r3_,tB3);                           \
    tA4=EFMA(hav_,r4_,tA4); tB4=EFMA(hbv_,r4_,tB4); } SB

#define REC10_2(RQ)                                                           \
    RECU2(RQ,0,hA0,hB0) RECU2(RQ,1,hA1,hB1) RECU2(RQ,2,hA2,hB2)               \
    RECU2(RQ,3,hA3,hB3) RECU2(RQ,4,hA4,hB4) RECU2(RQ,5,hA5,hB5)               \
    RECU2(RQ,6,hA6,hB6) RECU2(RQ,7,hA7,hB7) RECU2(RQ,8,hA8,hB8)               \
    RECU2(RQ,9,hA9,hB9)

// pair-A act: p = sig(i) * relu(g)
#define PACT(j)                                                               \
    pA##j = SIGS(ELA(j)) * fmaxf(ELA(10+(j)), 0.0f);                          \
    pB##j = SIGS(ELB(j)) * fmaxf(ELB(10+(j)), 0.0f);

// pair-B act: c = sig(f)*c + p ; h = sig(o)*relu(c)
#define CHACT(j)                                                              \
    cA##j = fmaf(SIGS(ELA(j)), cA##j, pA##j);                                 \
    hA##j = SIGS(ELA(10+(j))) * fmaxf(cA##j, 0.0f);                           \
    cB##j = fmaf(SIGS(ELB(j)), cB##j, pB##j);                                 \
    hB##j = SIGS(ELB(10+(j))) * fmaxf(cB##j, 0.0f);

#define STEP1_2(xa, xb)                                                       \
 {  int lof_ = 0;                                                             \
    asm volatile("" : "+v"(lof_));    /* block LICM of invariant loads */     \
    const float* wsl_ = smem + lof_;                                          \
    const floatx4* R1A_ = (const floatx4*)(wsl_);                             \
    const floatx4* R1B_ = (const floatx4*)(wsl_ + 200);                       \
    const floatx4* W1A_ = (const floatx4*)(wsl_ + 400);                       \
    const floatx4* W1B_ = (const floatx4*)(wsl_ + 420);                       \
    const floatx4* B1A_ = (const floatx4*)(wsl_ + 440);                       \
    const floatx4* B1B_ = (const floatx4*)(wsl_ + 460);                       \
    const float xa_ = (xa), xb_ = (xb);                                       \
    const floatx4 xsA_ = {xa_,xa_,xa_,xa_}, xsB_ = {xb_,xb_,xb_,xb_};         \
    floatx4 tA0,tA1,tA2,tA3,tA4, tB0,tB1,tB2,tB3,tB4;                         \
    float pA0,pA1,pA2,pA3,pA4,pA5,pA6,pA7,pA8,pA9;                            \
    float pB0,pB1,pB2,pB3,pB4,pB5,pB6,pB7,pB8,pB9;                            \
    INIT2(W1A_, B1A_) SB                                                      \
    REC10_2(R1A_)                     /* pair (i,g) */                        \
    PACT(0) PACT(1) PACT(2) PACT(3) PACT(4)                                   \
    PACT(5) PACT(6) PACT(7) PACT(8) PACT(9) SB                                \
    INIT2(W1B_, B1B_) SB                                                      \
    REC10_2(R1B_)                     /* pair (f,o); dot uses OLD h */        \
    CHACT(0) CHACT(1) CHACT(2) CHACT(3) CHACT(4)                              \
    CHACT(5) CHACT(6) CHACT(7) CHACT(8) CHACT(9) SB                           \
 }

// ---------------- single-element tail blocks --------------------------------
#define RECU1(RQ, u, HV)                                                      \
  { const floatx4 r0_=(RQ)[(u)*5+0], r1_=(RQ)[(u)*5+1], r2_=(RQ)[(u)*5+2],    \
                  r3_=(RQ)[(u)*5+3], r4_=(RQ)[(u)*5+4];                       \
    const float h_=(HV); const floatx4 hv_={h_,h_,h_,h_};                     \
    t0=EFMA(hv_,r0_,t0); t1=EFMA(hv_,r1_,t1); t2=EFMA(hv_,r2_,t2);            \
    t3=EFMA(hv_,r3_,t3); t4=EFMA(hv_,r4_,t4); } SB

#define REC10_1(RQ,g0,g1,g2,g3,g4,g5,g6,g7,g8,g9)                             \
    RECU1(RQ,0,g0) RECU1(RQ,1,g1) RECU1(RQ,2,g2) RECU1(RQ,3,g3)               \
    RECU1(RQ,4,g4) RECU1(RQ,5,g5) RECU1(RQ,6,g6) RECU1(RQ,7,g7)               \
    RECU1(RQ,8,g8) RECU1(RQ,9,g9)

#define TEL(k)  EL5(t0,t1,t2,t3,t4,(k))
#define XELA(k) EL5(xA0,xA1,xA2,xA3,xA4,(k))
#define XELB(k) EL5(xB0,xB1,xB2,xB3,xB4,(k))

// LSTM2 step t2>=1
#define TPA(j) p##j = SIGS(TEL(j)) * fmaxf(TEL(10+(j)), 0.0f);
#define TCH(j) c2##j = fmaf(SIGS(TEL(j)), c2##j, p##j);                       \
               h2##j = SIGS(TEL(10+(j))) * fmaxf(c2##j, 0.0f);

#define TSTEP                                                                 \
  { const float g0=h20,g1=h21,g2=h22,g3=h23,g4=h24;                           \
    const float g5=h25,g6=h26,g7=h27,g8=h28,g9=h29;                           \
    floatx4 t0,t1,t2,t3,t4;                                                   \
    float p0,p1,p2,p3,p4,p5,p6,p7,p8,p9;                                      \
    t0=xA0; t1=xA1; t2=xA2; t3=xA3; t4=xA4;                                   \
    REC10_1(R2A_,g0,g1,g2,g3,g4,g5,g6,g7,g8,g9)                               \
    TPA(0) TPA(1) TPA(2) TPA(3) TPA(4) TPA(5) TPA(6) TPA(7) TPA(8) TPA(9) SB  \
    t0=xB0; t1=xB1; t2=xB2; t3=xB3; t4=xB4;                                   \
    REC10_1(R2B_,g0,g1,g2,g3,g4,g5,g6,g7,g8,g9)                               \
    TCH(0) TCH(1) TCH(2) TCH(3) TCH(4) TCH(5) TCH(6) TCH(7) TCH(8) TCH(9) SB }

#define DSUM(dst)                                                             \
    dst = bd0;                                                                \
    dst = fmaf(h20,wd0,dst); dst = fmaf(h21,wd1,dst); dst = fmaf(h22,wd2,dst);\
    dst = fmaf(h23,wd3,dst); dst = fmaf(h24,wd4,dst); dst = fmaf(h25,wd5,dst);\
    dst = fmaf(h26,wd6,dst); dst = fmaf(h27,wd7,dst); dst = fmaf(h28,wd8,dst);\
    dst = fmaf(h29,wd9,dst);

__device__ __forceinline__ void tail_one(const float* __restrict__ smem,
    float v0, float v1, float v2, float v3, float v4,
    float v5, float v6, float v7, float v8, float v9,
    float bd0, float* __restrict__ o3)
{
    const floatx4* W2A_ = (const floatx4*)(smem + 480);
    const floatx4* W2B_ = (const floatx4*)(smem + 680);
    const floatx4* B2A_ = (const floatx4*)(smem + 880);
    const floatx4* B2B_ = (const floatx4*)(smem + 900);
    const floatx4* R2A_ = (const floatx4*)(smem + 920);
    const floatx4* R2B_ = (const floatx4*)(smem + 1120);
    const float wd0=smem[1320],wd1=smem[1321],wd2=smem[1322],wd3=smem[1323];
    const float wd4=smem[1324],wd5=smem[1325],wd6=smem[1326],wd7=smem[1327];
    const float wd8=smem[1328],wd9=smem[1329];

    // xz pairs, persist across the 3 repeated steps
    floatx4 xA0,xA1,xA2,xA3,xA4, xB0,xB1,xB2,xB3,xB4;
    {   floatx4 t0,t1,t2,t3,t4;
        t0=B2A_[0]; t1=B2A_[1]; t2=B2A_[2]; t3=B2A_[3]; t4=B2A_[4];
        REC10_1(W2A_,v0,v1,v2,v3,v4,v5,v6,v7,v8,v9)
        xA0=t0; xA1=t1; xA2=t2; xA3=t3; xA4=t4;
        t0=B2B_[0]; t1=B2B_[1]; t2=B2B_[2]; t3=B2B_[3]; t4=B2B_[4];
        REC10_1(W2B_,v0,v1,v2,v3,v4,v5,v6,v7,v8,v9)
        xB0=t0; xB1=t1; xB2=t2; xB3=t3; xB4=t4;
    }

    // t2 = 0: h_prev = c_prev = 0 -> c = sig(i)*relu(g); h = sig(o)*relu(c)
    float c20,c21,c22,c23,c24,c25,c26,c27,c28,c29;
    float h20,h21,h22,h23,h24,h25,h26,h27,h28,h29;
#define T0A(j)                                                                \
    c2##j = SIGS(XELA(j)) * fmaxf(XELA(10+(j)), 0.0f);                        \
    h2##j = SIGS(XELB(10+(j))) * fmaxf(c2##j, 0.0f);
    T0A(0) T0A(1) T0A(2) T0A(3) T0A(4) T0A(5) T0A(6) T0A(7) T0A(8) T0A(9)
#undef T0A

    float o0, o1, o2;
    DSUM(o0)
    TSTEP
    DSUM(o1)
    TSTEP
    DSUM(o2)
    o3[0] = o0; o3[1] = o1; o3[2] = o2;
}

__global__ __launch_bounds__(BLK) __attribute__((amdgpu_waves_per_eu(2)))
void lstm_ae_kernel(const float* __restrict__ X, const float* __restrict__ ws,
                    const float* __restrict__ bd, float* __restrict__ out, int B)
{
    __shared__ __align__(16) float smem[WS_FLOATS];    // 5.3 KB
    for (int i = threadIdx.x; i < WS_FLOATS; i += BLK) smem[i] = ws[i];
    __syncthreads();

    // M=2: rows b0 (element A) and b1 = b0 + BLK (element B)
    const int base = blockIdx.x * (2 * BLK);
    const int b0 = base + threadIdx.x;
    if (b0 >= B) return;
    int b1 = b0 + BLK;
    if (b1 >= B) b1 = b0;     // benign duplicate in non-exact tails

    // ---------------- LSTM 1: 50 steps, 2 elements/thread, all scalars -----
    float hA0=0,hA1=0,hA2=0,hA3=0,hA4=0,hA5=0,hA6=0,hA7=0,hA8=0,hA9=0;
    float cA0=0,cA1=0,cA2=0,cA3=0,cA4=0,cA5=0,cA6=0,cA7=0,cA8=0,cA9=0;
    float hB0=0,hB1=0,hB2=0,hB3=0,hB4=0,hB5=0,hB6=0,hB7=0,hB8=0,hB9=0;
    float cB0=0,cB1=0,cB2=0,cB3=0,cB4=0,cB5=0,cB6=0,cB7=0,cB8=0,cB9=0;

    const float2* __restrict__ xpa = (const float2*)(X + (size_t)b0 * TIN);
    const float2* __restrict__ xpb = (const float2*)(X + (size_t)b1 * TIN);
    float2 va = xpa[0], vb = xpb[0];
    #pragma unroll 1
    for (int p = 0; p < TIN / 2 - 1; ++p) {
        const float2 na = xpa[p + 1], nb = xpb[p + 1];
        STEP1_2(va.x, vb.x)
        STEP1_2(va.y, vb.y)
        va = na; vb = nb;
    }
    STEP1_2(va.x, vb.x)
    STEP1_2(va.y, vb.y)

    // ---------------- tails, sequential per element ----------------
    const float bd0 = bd[0];
    tail_one(smem, hA0,hA1,hA2,hA3,hA4,hA5,hA6,hA7,hA8,hA9, bd0,
             out + (size_t)b0 * 3);
    tail_one(smem, hB0,hB1,hB2,hB3,hB4,hB5,hB6,hB7,hB8,hB9, bd0,
             out + (size_t)b1 * 3);
}

extern "C" void kernel_launch(void* const* d_in, const int* in_sizes, int n_in,
                              void* d_out, int out_size, void* d_ws, size_t ws_size,
                              hipStream_t stream) {
    const float* X  = (const float*)d_in[0];
    const float* W1 = (const float*)d_in[1];
    const float* R1 = (const float*)d_in[2];
    const float* b1 = (const float*)d_in[3];
    const float* W2 = (const float*)d_in[4];
    const float* R2 = (const float*)d_in[5];
    const float* b2 = (const float*)d_in[6];
    const float* Wd = (const float*)d_in[7];
    const float* bd = (const float*)d_in[8];
    float* out = (float*)d_out;
    float* ws  = (float*)d_ws;

    const int B = in_sizes[0] / TIN;   // 524288
    prep_weights<<<1, BLK, 0, stream>>>(W1, R1, b1, W2, R2, b2, Wd, ws);
    const int grid = (B + 2 * BLK - 1) / (2 * BLK);   // 1024
    lstm_ae_kernel<<<grid, BLK, 0, stream>>>(X, ws, bd, out, B);
}

// Round 16
// 440.856 us; speedup vs baseline: 9.9518x; 9.9518x over previous
//
#include <hip/hip_runtime.h>

constexpr int TIN = 50;
constexpr int BLK = 256;
constexpr float NEG_LOG2E = -1.44269504088896341f;

typedef float floatx4 __attribute__((ext_vector_type(4)));

// ws float layout (16B-aligned, gate-major, 10->12 pad so quads are single-gate).
// k = gate*12 + j, gate {0:i,1:f,2:g,3:o}; i/f/o cols pre-scaled by -log2(e)
// so sigmoid(z) = rcp(1 + exp2(z')).
//   0    R1p[10][48]
//   480  W1p[48]
//   528  b1p[48]
//   576  W2p[10][48]
//   1056 b2p[48]
//   1104 R2p[10][48]
//   1584 Wdp[12]
constexpr int WS_FLOATS = 1596;

__global__ void prep_weights(const float* __restrict__ W1, const float* __restrict__ R1,
                             const float* __restrict__ b1, const float* __restrict__ W2,
                             const float* __restrict__ R2, const float* __restrict__ b2,
                             const float* __restrict__ Wd, float* __restrict__ ws)
{
    const int tid = threadIdx.x;
    for (int i = tid; i < 480; i += BLK) {
        const int u = i / 48, k = i % 48, gate = k / 12, j = k % 12;
        const float sg = (gate == 2) ? 1.0f : NEG_LOG2E;
        ws[i]        = (j < 10) ? R1[u * 40 + gate * 10 + j] * sg : 0.0f;
        ws[576 + i]  = (j < 10) ? W2[u * 40 + gate * 10 + j] * sg : 0.0f;
        ws[1104 + i] = (j < 10) ? R2[u * 40 + gate * 10 + j] * sg : 0.0f;
    }
    for (int k = tid; k < 48; k += BLK) {
        const int gate = k / 12, j = k % 12;
        const float sg = (gate == 2) ? 1.0f : NEG_LOG2E;
        ws[480 + k]  = (j < 10) ? W1[gate * 10 + j] * sg : 0.0f;
        ws[528 + k]  = (j < 10) ? b1[gate * 10 + j] * sg : 0.0f;
        ws[1056 + k] = (j < 10) ? b2[gate * 10 + j] * sg : 0.0f;
    }
    if (tid < 12) ws[1584 + tid] = (tid < 10) ? Wd[tid] : 0.0f;
}

#define EFMA __builtin_elementwise_fma
#define EMAX __builtin_elementwise_max
#define SB   __builtin_amdgcn_sched_barrier(0);

#define SIGQ(dst, src)                                                        \
    dst[0] = __builtin_amdgcn_rcpf(1.0f + __builtin_amdgcn_exp2f((src)[0]));  \
    dst[1] = __builtin_amdgcn_rcpf(1.0f + __builtin_amdgcn_exp2f((src)[1]));  \
    dst[2] = __builtin_amdgcn_rcpf(1.0f + __builtin_amdgcn_exp2f((src)[2]));  \
    dst[3] = __builtin_amdgcn_rcpf(1.0f + __builtin_amdgcn_exp2f((src)[3]));

#define SIG3(d0, d1, d2, s0, s1, s2) SIGQ(d0, s0) SIGQ(d1, s1) SIGQ(d2, s2)

// ---------------- single-element building blocks (tail; = round 10/14) ------
#define RECQ(RB, g, u, HV, t0, t1, t2)                                        \
    {   const float h_ = (HV);                                                \
        const floatx4 hs_ = {h_, h_, h_, h_};                                 \
        t0 = EFMA(hs_, RB[(u) * 12 + (g) * 3 + 0], t0);                       \
        t1 = EFMA(hs_, RB[(u) * 12 + (g) * 3 + 1], t1);                       \
        t2 = EFMA(hs_, RB[(u) * 12 + (g) * 3 + 2], t2); }

#define REC10(RB, g, H0, H1, H2, t0, t1, t2)                                  \
    RECQ(RB, g, 0, (H0)[0], t0, t1, t2) RECQ(RB, g, 1, (H0)[1], t0, t1, t2) SB\
    RECQ(RB, g, 2, (H0)[2], t0, t1, t2) RECQ(RB, g, 3, (H0)[3], t0, t1, t2) SB\
    RECQ(RB, g, 4, (H1)[0], t0, t1, t2) RECQ(RB, g, 5, (H1)[1], t0, t1, t2) SB\
    RECQ(RB, g, 6, (H1)[2], t0, t1, t2) RECQ(RB, g, 7, (H1)[3], t0, t1, t2) SB\
    RECQ(RB, g, 8, (H2)[0], t0, t1, t2) RECQ(RB, g, 9, (H2)[1], t0, t1, t2) SB

#define XZG(g, x0, x1, x2)                                                    \
    x0 = B2q_[(g) * 3 + 0]; x1 = B2q_[(g) * 3 + 1]; x2 = B2q_[(g) * 3 + 2];   \
    REC10(W2q_, g, hq0, hq1, hq2, x0, x1, x2)

#define GATE2(g, i0, i1, i2, t0, t1, t2)                                      \
    t0 = i0; t1 = i1; t2 = i2;                                                \
    REC10(R2q_, g, ho0, ho1, ho2, t0, t1, t2)

#define STEP2T                                                                \
    {   const floatx4 ho0 = h2q0, ho1 = h2q1, ho2 = h2q2;                     \
        floatx4 tt0, tt1, tt2, pp0, pp1, pp2, qq0, qq1, qq2;                  \
        GATE2(2, xqg0, xqg1, xqg2, tt0, tt1, tt2)                             \
        pp0 = EMAX(tt0, zero4); pp1 = EMAX(tt1, zero4);                       \
        pp2 = EMAX(tt2, zero4); SB                                            \
        GATE2(0, xqi0, xqi1, xqi2, tt0, tt1, tt2)                             \
        SIG3(qq0, qq1, qq2, tt0, tt1, tt2)                                    \
        pp0 *= qq0; pp1 *= qq1; pp2 *= qq2; SB                                \
        GATE2(1, xqf0, xqf1, xqf2, tt0, tt1, tt2)                             \
        SIG3(qq0, qq1, qq2, tt0, tt1, tt2)                                    \
        c2q0 = EFMA(qq0, c2q0, pp0); c2q1 = EFMA(qq1, c2q1, pp1);             \
        c2q2 = EFMA(qq2, c2q2, pp2); SB                                       \
        GATE2(3, xqo0, xqo1, xqo2, tt0, tt1, tt2)                             \
        SIG3(qq0, qq1, qq2, tt0, tt1, tt2)                                    \
        h2q0 = qq0 * EMAX(c2q0, zero4); h2q1 = qq1 * EMAX(c2q1, zero4);       \
        h2q2 = qq2 * EMAX(c2q2, zero4); SB                                    \
    }

#define DOUT(dst)                                                             \
    {   floatx4 dv_ = h2q0 * Wdq_[0];                                         \
        dv_ = EFMA(h2q1, Wdq_[1], dv_);                                       \
        dv_ = EFMA(h2q2, Wdq_[2], dv_);                                       \
        dst = dv_[0] + dv_[1] + dv_[2] + dv_[3] + bd0; }

// RepeatVector(3) + LSTM2 + Dense for ONE element (all names compile-time)
__device__ __forceinline__ void tail_one(const float* __restrict__ smem,
                                         floatx4 hq0, floatx4 hq1, floatx4 hq2,
                                         float bd0, float* __restrict__ o3)
{
    const floatx4 zero4 = {0.0f, 0.0f, 0.0f, 0.0f};
    const floatx4* W2q_ = (const floatx4*)(smem + 576);
    const floatx4* B2q_ = (const floatx4*)(smem + 1056);
    const floatx4* R2q_ = (const floatx4*)(smem + 1104);
    const floatx4* Wdq_ = (const floatx4*)(smem + 1584);

    floatx4 xqi0, xqi1, xqi2, xqf0, xqf1, xqf2;
    floatx4 xqg0, xqg1, xqg2, xqo0, xqo1, xqo2;
    XZG(0, xqi0, xqi1, xqi2) SB
    XZG(1, xqf0, xqf1, xqf2) SB
    XZG(2, xqg0, xqg1, xqg2) SB
    XZG(3, xqo0, xqo1, xqo2) SB

    floatx4 c2q0, c2q1, c2q2, h2q0, h2q1, h2q2, q0, q1, q2, s0, s1, s2;
    SIG3(q0, q1, q2, xqi0, xqi1, xqi2)
    c2q0 = q0 * EMAX(xqg0, zero4);
    c2q1 = q1 * EMAX(xqg1, zero4);
    c2q2 = q2 * EMAX(xqg2, zero4);
    SIG3(s0, s1, s2, xqo0, xqo1, xqo2)
    h2q0 = s0 * EMAX(c2q0, zero4);
    h2q1 = s1 * EMAX(c2q1, zero4);
    h2q2 = s2 * EMAX(c2q2, zero4);
    float o0; DOUT(o0)
    float o1; STEP2T DOUT(o1)
    float o2; STEP2T DOUT(o2)
    o3[0] = o0; o3[1] = o1; o3[2] = o2;
}

// ---------------- M=2 main-loop blocks with 1-unit lookahead ----------------
// LDU: issue 3 shared quad loads for unit u into named set (12 regs).
#define LDU(RB, g, u, d0, d1, d2)                                             \
    d0 = RB[(u) * 12 + (g) * 3 + 0];                                          \
    d1 = RB[(u) * 12 + (g) * 3 + 1];                                          \
    d2 = RB[(u) * 12 + (g) * 3 + 2];

// FMAU: consume one 3-quad set for both elements (12 scalar FMAs).
#define FMAU(HA, HB, r0, r1, r2)                                              \
    {   const float ha_ = (HA), hb_ = (HB);                                   \
        const floatx4 hav_ = {ha_, ha_, ha_, ha_};                            \
        const floatx4 hbv_ = {hb_, hb_, hb_, hb_};                            \
        tA0 = EFMA(hav_, r0, tA0); tB0 = EFMA(hbv_, r0, tB0);                 \
        tA1 = EFMA(hav_, r1, tA1); tB1 = EFMA(hbv_, r1, tB1);                 \
        tA2 = EFMA(hav_, r2, tA2); tB2 = EFMA(hbv_, r2, tB2); }

// Windows: {load u+1 ; FMA u ; SB} — load-to-use distance = one full window,
// halving the per-window lgkmcnt stall vs round 14's load-then-consume.
// ra*/rb* ping-pong: only ONE 3-quad set (12 regs) is live across each SB.
#define REC10_2T(RB, g)                                                       \
    LDU(RB, g, 1, rb0, rb1, rb2) FMAU(hA0[0], hB0[0], ra0, ra1, ra2) SB       \
    LDU(RB, g, 2, ra0, ra1, ra2) FMAU(hA0[1], hB0[1], rb0, rb1, rb2) SB       \
    LDU(RB, g, 3, rb0, rb1, rb2) FMAU(hA0[2], hB0[2], ra0, ra1, ra2) SB       \
    LDU(RB, g, 4, ra0, ra1, ra2) FMAU(hA0[3], hB0[3], rb0, rb1, rb2) SB       \
    LDU(RB, g, 5, rb0, rb1, rb2) FMAU(hA1[0], hB1[0], ra0, ra1, ra2) SB       \
    LDU(RB, g, 6, ra0, ra1, ra2) FMAU(hA1[1], hB1[1], rb0, rb1, rb2) SB       \
    LDU(RB, g, 7, rb0, rb1, rb2) FMAU(hA1[2], hB1[2], ra0, ra1, ra2) SB       \
    LDU(RB, g, 8, ra0, ra1, ra2) FMAU(hA1[3], hB1[3], rb0, rb1, rb2) SB       \
    LDU(RB, g, 9, rb0, rb1, rb2) FMAU(hA2[0], hB2[0], ra0, ra1, ra2) SB       \
    FMAU(hA2[1], hB2[1], rb0, rb1, rb2) SB

// gate pre-activation: prefetch unit 0, init t from W/b, then windowed dot
#define GATE1_2(g)                                                            \
    LDU(Rq_, g, 0, ra0, ra1, ra2)                                             \
    {   const floatx4 w0_ = Wq_[(g)*3+0], w1_ = Wq_[(g)*3+1],                 \
                      w2_ = Wq_[(g)*3+2];                                     \
        const floatx4 b0_ = Bq_[(g)*3+0], b1_ = Bq_[(g)*3+1],                 \
                      b2_ = Bq_[(g)*3+2];                                     \
        tA0 = EFMA(xsA_, w0_, b0_); tB0 = EFMA(xsB_, w0_, b0_);               \
        tA1 = EFMA(xsA_, w1_, b1_); tB1 = EFMA(xsB_, w1_, b1_);               \
        tA2 = EFMA(xsA_, w2_, b2_); tB2 = EFMA(xsB_, w2_, b2_); } SB          \
    REC10_2T(Rq_, g)

#define STEP1_2(xa, xb)                                                       \
    {   int lof_ = 0;                                                         \
        asm volatile("" : "+v"(lof_));    /* block LICM of invariant loads */ \
        const floatx4* Rq_ = (const floatx4*)(smem + lof_);                   \
        const floatx4* Wq_ = (const floatx4*)(smem + 480 + lof_);             \
        const floatx4* Bq_ = (const floatx4*)(smem + 528 + lof_);             \
        const float xa_ = (xa), xb_ = (xb);                                   \
        const floatx4 xsA_ = {xa_, xa_, xa_, xa_};                            \
        const floatx4 xsB_ = {xb_, xb_, xb_, xb_};                            \
        floatx4 tA0, tA1, tA2, tB0, tB1, tB2;                                 \
        floatx4 pA0, pA1, pA2, pB0, pB1, pB2;                                 \
        floatx4 qA0, qA1, qA2, qB0, qB1, qB2;                                 \
        floatx4 ra0, ra1, ra2, rb0, rb1, rb2;                                 \
        GATE1_2(2)   /* g: relu */                                            \
        pA0 = EMAX(tA0, zero4); pA1 = EMAX(tA1, zero4); pA2 = EMAX(tA2, zero4);\
        pB0 = EMAX(tB0, zero4); pB1 = EMAX(tB1, zero4); pB2 = EMAX(tB2, zero4);\
        SB                                                                    \
        GATE1_2(0)   /* i */                                                  \
        SIG3(qA0, qA1, qA2, tA0, tA1, tA2)                                    \
        SIG3(qB0, qB1, qB2, tB0, tB1, tB2)                                    \
        pA0 *= qA0; pA1 *= qA1; pA2 *= qA2;                                   \
        pB0 *= qB0; pB1 *= qB1; pB2 *= qB2; SB                                \
        GATE1_2(1)   /* f */                                                  \
        SIG3(qA0, qA1, qA2, tA0, tA1, tA2)                                    \
        SIG3(qB0, qB1, qB2, tB0, tB1, tB2)                                    \
        cA0 = EFMA(qA0, cA0, pA0); cA1 = EFMA(qA1, cA1, pA1);                 \
        cA2 = EFMA(qA2, cA2, pA2);                                            \
        cB0 = EFMA(qB0, cB0, pB0); cB1 = EFMA(qB1, cB1, pB1);                 \
        cB2 = EFMA(qB2, cB2, pB2); SB                                         \
        GATE1_2(3)   /* o (dot uses old h; h written after) */                \
        SIG3(qA0, qA1, qA2, tA0, tA1, tA2)                                    \
        SIG3(qB0, qB1, qB2, tB0, tB1, tB2)                                    \
        hA0 = qA0 * EMAX(cA0, zero4); hA1 = qA1 * EMAX(cA1, zero4);           \
        hA2 = qA2 * EMAX(cA2, zero4);                                         \
        hB0 = qB0 * EMAX(cB0, zero4); hB1 = qB1 * EMAX(cB1, zero4);           \
        hB2 = qB2 * EMAX(cB2, zero4); SB                                      \
    }

// min=2 keeps the RA budget that produced the clean M=2 schedule (round 14);
// no max so residency follows actual VGPR use.
__global__ __launch_bounds__(BLK) __attribute__((amdgpu_waves_per_eu(2)))
void lstm_ae_kernel(const float* __restrict__ X, const float* __restrict__ ws,
                    const float* __restrict__ bd, float* __restrict__ out, int B)
{
    __shared__ __align__(16) float smem[WS_FLOATS];    // 6.4 KB
    for (int i = threadIdx.x; i < WS_FLOATS; i += BLK) smem[i] = ws[i];
    __syncthreads();

    // M=2: rows b0 (element A) and b1 = b0 + BLK (element B)
    const int base = blockIdx.x * (2 * BLK);
    const int b0 = base + threadIdx.x;
    if (b0 >= B) return;
    int b1 = b0 + BLK;
    if (b1 >= B) b1 = b0;     // benign duplicate in non-exact tails

    const floatx4 zero4 = {0.0f, 0.0f, 0.0f, 0.0f};

    // ---------------- LSTM 1: 50 steps, 2 elements/thread ----------------
    floatx4 hA0 = zero4, hA1 = zero4, hA2 = zero4;
    floatx4 cA0 = zero4, cA1 = zero4, cA2 = zero4;
    floatx4 hB0 = zero4, hB1 = zero4, hB2 = zero4;
    floatx4 cB0 = zero4, cB1 = zero4, cB2 = zero4;

    const float2* __restrict__ xpa = (const float2*)(X + (size_t)b0 * TIN);
    const float2* __restrict__ xpb = (const float2*)(X + (size_t)b1 * TIN);
    float2 va = xpa[0], vb = xpb[0];
    #pragma unroll 1
    for (int p = 0; p < TIN / 2 - 1; ++p) {
        const float2 na = xpa[p + 1], nb = xpb[p + 1];
        STEP1_2(va.x, vb.x)
        STEP1_2(va.y, vb.y)
        va = na; vb = nb;
    }
    STEP1_2(va.x, vb.x)
    STEP1_2(va.y, vb.y)

    // ---------------- tails, sequential per element ----------------
    const float bd0 = bd[0];
    tail_one(smem, hA0, hA1, hA2, bd0, out + (size_t)b0 * 3);
    tail_one(smem, hB0, hB1, hB2, bd0, out + (size_t)b1 * 3);
}

extern "C" void kernel_launch(void* const* d_in, const int* in_sizes, int n_in,
                              void* d_out, int out_size, void* d_ws, size_t ws_size,
                              hipStream_t stream) {
    const float* X  = (const float*)d_in[0];
    const float* W1 = (const float*)d_in[1];
    const float* R1 = (const float*)d_in[2];
    const float* b1 = (const float*)d_in[3];
    const float* W2 = (const float*)d_in[4];
    const float* R2 = (const float*)d_in[5];
    const float* b2 = (const float*)d_in[6];
    const float* Wd = (const float*)d_in[7];
    const float* bd = (const float*)d_in[8];
    float* out = (float*)d_out;
    float* ws  = (float*)d_ws;

    const int B = in_sizes[0] / TIN;   // 524288
    prep_weights<<<1, BLK, 0, stream>>>(W1, R1, b1, W2, R2, b2, Wd, ws);
    const int grid = (B + 2 * BLK - 1) / (2 * BLK);   // 1024
    lstm_ae_kernel<<<grid, BLK, 0, stream>>>(X, ws, bd, out, B);
}